// Round 9
// baseline (169.552 us; speedup 1.0000x reference)
//
#include <hip/hip_runtime.h>

#define TOKENS 16384
#define EMB 4096
#define NEXP 64

typedef __attribute__((ext_vector_type(8))) short short8;
typedef __attribute__((ext_vector_type(4))) float f32x4;
typedef __attribute__((ext_vector_type(4))) unsigned short ush4;

#define WP_USHORTS (3 * NEXP * EMB)        // 1.5 MB bf16 W-planes (L2-resident)
#define WP_FLOATS  (WP_USHORTS / 2)

// fp32 -> 3x bf16 (R7/R8-verified exact: absmax 0.0): hi RN, mid/lo trunc.
__device__ __forceinline__ void split3(float x, unsigned short& h,
                                       unsigned short& m, unsigned short& l) {
    unsigned u = __float_as_uint(x);
    unsigned r = u + 0x7FFFu + ((u >> 16) & 1u);
    float hF = __uint_as_float(r & 0xFFFF0000u);
    h = (unsigned short)(r >> 16);
    float r1 = x - hF;
    unsigned u1 = __float_as_uint(r1);
    float mF = __uint_as_float(u1 & 0xFFFF0000u);
    m = (unsigned short)(u1 >> 16);
    float r2 = r1 - mF;
    l = (unsigned short)(__float_as_uint(r2) >> 16);
}

// prep: split W into 3 bf16 planes Wp[plane][e][k]
__global__ __launch_bounds__(256) void split_w(const float* __restrict__ W,
                                               unsigned short* __restrict__ Wp) {
    const int i = (blockIdx.x * 256 + threadIdx.x) * 4;
    const float4 v = *reinterpret_cast<const float4*>(W + i);
    ush4 h, m, l;
#pragma unroll
    for (int e = 0; e < 4; ++e) {
        unsigned short he, me, le;
        split3(reinterpret_cast<const float*>(&v)[e], he, me, le);
        h[e] = he; m[e] = me; l[e] = le;
    }
    *reinterpret_cast<ush4*>(Wp + i) = h;
    *reinterpret_cast<ush4*>(Wp + NEXP * EMB + i) = m;
    *reinterpret_cast<ush4*>(Wp + 2 * NEXP * EMB + i) = l;
}

// Main: MFMA split-3 bf16, BARRIER-FREE all-register K-loop.
// R8 was ~2x the HBM floor because every per-step __syncthreads drained
// vmcnt(0), exposing HBM latency. Fix: no LDS, no barriers in the loop.
// Wave = 32 tokens x 32 experts (2x2 16x16 tiles); block = 4 waves =
// 64 tok x 64 exp; grid (256, S). Per step: A = 4 global float4 (HBM,
// streamed once; token-half dup absorbed by L2), B = 6 short8 direct
// from L2-resident Wp (0.8 GB L2 total = ~23 us chip, 2x below R7's
// fatal level thanks to the 32-expert tile), split3 in-reg, 24 MFMA.
// unroll 2 + 4 independent waves/SIMD hide L2/HBM latency dynamically.
// Frag maps identical to R7/R8 (HW-verified exact): A row=l&15,
// k=(l>>4)*8+e; B col=l&15 same k map; D col(expert)=l&15,
// row(token)=(l>>4)*4+j. Precision identical: RN hi + trunc m/l,
// 6 terms, hh segregated in accH.
template<int S>
__global__ __launch_bounds__(256, 4) void router_mfma(
    const float* __restrict__ x, const unsigned short* __restrict__ Wp,
    float* __restrict__ part)
{
    constexpr int KPER = EMB / S;
    constexpr int NST  = KPER / 32;

    __shared__ float sled[4][32][33];   // 16.9 KB, epilogue transpose only

    const int t  = threadIdx.x;
    const int w  = t >> 6;
    const int l  = t & 63;
    const int lr = l & 15;     // A token-row / B expert-col
    const int lo = l >> 4;     // k-octet selector
    const int wr = w >> 1;     // token half  (0/1)
    const int wc = w & 1;      // expert half (0/1)
    const int tok0 = blockIdx.x * 64 + 32 * wr;
    const int kb   = blockIdx.y * KPER;

    const float* ax[2];
    ax[0] = x + (size_t)(tok0 + lr) * EMB + kb + lo * 8;
    ax[1] = x + (size_t)(tok0 + 16 + lr) * EMB + kb + lo * 8;
    const unsigned short* bw[2];
    bw[0] = Wp + (size_t)(32 * wc + lr) * EMB + kb + lo * 8;
    bw[1] = bw[0] + (size_t)16 * EMB;

    f32x4 accH[2][2], accL[2][2];
#pragma unroll
    for (int ti = 0; ti < 2; ++ti)
#pragma unroll
        for (int et = 0; et < 2; ++et) {
            accH[ti][et] = (f32x4){0.f, 0.f, 0.f, 0.f};
            accL[ti][et] = (f32x4){0.f, 0.f, 0.f, 0.f};
        }

#pragma unroll 2
    for (int ks = 0; ks < NST; ++ks) {
        const int ck = ks * 32;
        // B for this step: 6 direct L2 loads (latency covered by split VALU)
        short8 bH[2], bM[2], bL[2];
#pragma unroll
        for (int et = 0; et < 2; ++et) {
            bH[et] = *reinterpret_cast<const short8*>(bw[et] + ck);
            bM[et] = *reinterpret_cast<const short8*>(bw[et] + NEXP * EMB + ck);
            bL[et] = *reinterpret_cast<const short8*>(bw[et] + 2 * NEXP * EMB + ck);
        }
#pragma unroll
        for (int ti = 0; ti < 2; ++ti) {
            const float4 a0 = *reinterpret_cast<const float4*>(ax[ti] + ck);
            const float4 a1 = *reinterpret_cast<const float4*>(ax[ti] + ck + 4);
            short8 aH, aM, aL;
#pragma unroll
            for (int e = 0; e < 4; ++e) {
                unsigned short he, me, le;
                split3(reinterpret_cast<const float*>(&a0)[e], he, me, le);
                aH[e] = (short)he; aM[e] = (short)me; aL[e] = (short)le;
                split3(reinterpret_cast<const float*>(&a1)[e], he, me, le);
                aH[4 + e] = (short)he; aM[4 + e] = (short)me; aL[4 + e] = (short)le;
            }
#pragma unroll
            for (int et = 0; et < 2; ++et) {
                accH[ti][et] = __builtin_amdgcn_mfma_f32_16x16x32_bf16(aH, bH[et], accH[ti][et], 0, 0, 0);
                accL[ti][et] = __builtin_amdgcn_mfma_f32_16x16x32_bf16(aH, bM[et], accL[ti][et], 0, 0, 0);
                accL[ti][et] = __builtin_amdgcn_mfma_f32_16x16x32_bf16(aM, bH[et], accL[ti][et], 0, 0, 0);
                accL[ti][et] = __builtin_amdgcn_mfma_f32_16x16x32_bf16(aM, bM[et], accL[ti][et], 0, 0, 0);
                accL[ti][et] = __builtin_amdgcn_mfma_f32_16x16x32_bf16(aH, bL[et], accL[ti][et], 0, 0, 0);
                accL[ti][et] = __builtin_amdgcn_mfma_f32_16x16x32_bf16(aL, bH[et], accL[ti][et], 0, 0, 0);
            }
        }
    }

    // epilogue: per-wave LDS transpose (no cross-wave sharing -> no barrier;
    // compiler inserts lgkmcnt for the same-wave ds dependency).
    // write banks: addr/4 = lr*33 + lo*4 + const -> <=4-way, 16 instrs only.
#pragma unroll
    for (int ti = 0; ti < 2; ++ti)
#pragma unroll
        for (int et = 0; et < 2; ++et)
#pragma unroll
            for (int j = 0; j < 4; ++j)
                sled[w][et * 16 + lr][ti * 16 + lo * 4 + j]
                    = accH[ti][et][j] + accL[ti][et][j];
    // coalesced partial writes: 2 expert-rows x 32 contiguous tokens / instr
#pragma unroll
    for (int r = 0; r < 16; ++r) {
        const int er = 2 * r + (l >> 5);
        part[(size_t)(blockIdx.y * NEXP + 32 * wc + er) * TOKENS
             + tok0 + (l & 31)] = sled[w][er][l & 31];
    }
}

// combine splits in fp64 + bias, top-2, softmax (R6/R7/R8-proven).
template<int S>
__global__ __launch_bounds__(256) void reduce_topk(
    const float* __restrict__ part, const float* __restrict__ b,
    float* __restrict__ out)
{
    __shared__ double sv[64][4][2];
    __shared__ int    si[64][4][2];
    const int t    = threadIdx.x;
    const int p4   = t & 3;
    const int slot = t >> 2;
    const int tok  = blockIdx.x * 64 + slot;

    double v[16];
#pragma unroll
    for (int j = 0; j < 16; ++j) v[j] = 0.0;
    for (int s = 0; s < S; ++s)
#pragma unroll
        for (int j = 0; j < 16; ++j)
            v[j] += (double)part[(size_t)((s << 6) + (p4 << 4) + j) * TOKENS + tok];
#pragma unroll
    for (int j = 0; j < 16; ++j) v[j] += (double)b[(p4 << 4) + j];

    double v1 = -1e300, v2 = -1e300; int i1 = 0, i2 = 0;
#pragma unroll
    for (int j = 0; j < 16; ++j) {
        const int e = (p4 << 4) + j;
        if (v[j] > v1)      { v2 = v1; i2 = i1; v1 = v[j]; i1 = e; }
        else if (v[j] > v2) { v2 = v[j]; i2 = e; }
    }
    sv[slot][p4][0] = v1; sv[slot][p4][1] = v2;
    si[slot][p4][0] = i1; si[slot][p4][1] = i2;
    __syncthreads();

    if (p4 == 0) {
        double m1 = -1e300, m2 = -1e300; int j1 = 0, j2 = 0;
#pragma unroll
        for (int p = 0; p < 4; ++p)   // ascending parts: ties keep lowest idx
#pragma unroll
            for (int r = 0; r < 2; ++r) {
                const double vv = sv[slot][p][r]; const int ii = si[slot][p][r];
                if (vv > m1)      { m2 = m1; j2 = j1; m1 = vv; j1 = ii; }
                else if (vv > m2) { m2 = vv; j2 = ii; }
            }
        const float e2  = expf((float)(m2 - m1));   // <= 1
        const float inv = 1.0f / (1.0f + e2);
        out[2 * tok]     = (float)j1;
        out[2 * tok + 1] = (float)j2;
        out[2 * TOKENS + 2 * tok]     = inv;
        out[2 * TOKENS + 2 * tok + 1] = e2 * inv;
    }
}

extern "C" void kernel_launch(void* const* d_in, const int* in_sizes, int n_in,
                              void* d_out, int out_size, void* d_ws, size_t ws_size,
                              hipStream_t stream) {
    const float* x = (const float*)d_in[0];
    const float* W = (const float*)d_in[1];
    const float* b = (const float*)d_in[2];
    float* out = (float*)d_out;
    unsigned short* Wp = (unsigned short*)d_ws;
    float* part = (float*)d_ws + WP_FLOATS;

    split_w<<<dim3(NEXP * EMB / 1024), dim3(256), 0, stream>>>(W, Wp);

    const size_t base = (size_t)WP_FLOATS * 4;
    const size_t per  = (size_t)NEXP * TOKENS * 4;   // 4.19 MB / split
    if (ws_size >= base + 4 * per) {         // 18.3 MB (proven R7/R8) -> 4/CU
        router_mfma<4><<<dim3(TOKENS / 64, 4), dim3(256), 0, stream>>>(x, Wp, part);
        reduce_topk<4><<<dim3(TOKENS / 64), dim3(256), 0, stream>>>(part, b, out);
    } else if (ws_size >= base + 2 * per) {
        router_mfma<2><<<dim3(TOKENS / 64, 2), dim3(256), 0, stream>>>(x, Wp, part);
        reduce_topk<2><<<dim3(TOKENS / 64), dim3(256), 0, stream>>>(part, b, out);
    } else {
        router_mfma<1><<<dim3(TOKENS / 64, 1), dim3(256), 0, stream>>>(x, Wp, part);
        reduce_topk<1><<<dim3(TOKENS / 64), dim3(256), 0, stream>>>(part, b, out);
    }
}

// Round 10
// 83.066 us; speedup vs baseline: 2.0412x; 2.0412x over previous
//
#include <hip/hip_runtime.h>

#define TOKENS 16384
#define EMB 4096
#define NEXP 64
#define BK 64

typedef __attribute__((ext_vector_type(8))) short short8;
typedef __attribute__((ext_vector_type(4))) float f32x4;
typedef __attribute__((ext_vector_type(4))) unsigned short ush4;

#define WP_USHORTS (3 * NEXP * EMB)        // 1.5 MB bf16 W-planes (L2-resident)
#define WP_FLOATS  (WP_USHORTS / 2)

// async global->LDS, 16B/lane; dest = wave-uniform base + lane*16 (source per-lane)
__device__ __forceinline__ void gl_lds16(const void* g, void* lds) {
    __builtin_amdgcn_global_load_lds(
        (const __attribute__((address_space(1))) void*)g,
        (__attribute__((address_space(3))) void*)lds, 16, 0, 0);
}

// fp32 -> 3x bf16 (R7/R8/R9-verified exact: absmax 0.0): hi RN, mid/lo trunc.
__device__ __forceinline__ void split3(float x, unsigned short& h,
                                       unsigned short& m, unsigned short& l) {
    unsigned u = __float_as_uint(x);
    unsigned r = u + 0x7FFFu + ((u >> 16) & 1u);
    float hF = __uint_as_float(r & 0xFFFF0000u);
    h = (unsigned short)(r >> 16);
    float r1 = x - hF;
    unsigned u1 = __float_as_uint(r1);
    float mF = __uint_as_float(u1 & 0xFFFF0000u);
    m = (unsigned short)(u1 >> 16);
    float r2 = r1 - mF;
    l = (unsigned short)(__float_as_uint(r2) >> 16);
}

// prep: split W into 3 bf16 planes Wp[plane][e][k] (flat row r = plane*64+e)
__global__ __launch_bounds__(256) void split_w(const float* __restrict__ W,
                                               unsigned short* __restrict__ Wp) {
    const int i = (blockIdx.x * 256 + threadIdx.x) * 4;
    const float4 v = *reinterpret_cast<const float4*>(W + i);
    ush4 h, m, l;
#pragma unroll
    for (int e = 0; e < 4; ++e) {
        unsigned short he, me, le;
        split3(reinterpret_cast<const float*>(&v)[e], he, me, le);
        h[e] = he; m[e] = me; l[e] = le;
    }
    *reinterpret_cast<ush4*>(Wp + i) = h;
    *reinterpret_cast<ush4*>(Wp + NEXP * EMB + i) = m;
    *reinterpret_cast<ush4*>(Wp + 2 * NEXP * EMB + i) = l;
}

// Main: MFMA split-3 bf16. R8 skeleton (B via global_load_lds double-buffer,
// stage + A-prefetch issued right AFTER the barrier), with the cover window
// doubled: BK=64, 512-thr block (8 waves x 16 tok = 128 tokens; each wave
// still 16 tok x 64 exp). Compute per barrier ~48 MFMA + 24 ds_read + 256
// VALU ~ 500-600 cyc ~ HBM latency, so the vmcnt(0) drain at the next
// __syncthreads finds the in-flight stage landed (R8's exposure was ~500
// cyc/step; R9 showed reg-only B is worse: compiler won't pipeline).
// grid (128,S): S=4 -> 512 blocks = exactly 2/CU (two staggered barrier
// groups per CU). Frag maps + precision identical to R7/R8/R9 (absmax 0.0).
template<int S>
__global__ __launch_bounds__(512, 4) void router_mfma(
    const float* __restrict__ x, const unsigned short* __restrict__ Wp,
    float* __restrict__ part)
{
    constexpr int KPER = EMB / S;
    constexpr int NCH  = KPER / BK;

    __shared__ unsigned short sB[2][192][BK];   // 48 KB (2 bufs x 24 KB)

    const int t  = threadIdx.x;
    const int w  = t >> 6;     // wave 0..7
    const int l  = t & 63;
    const int lr = l & 15;     // A token-row / B expert-col
    const int lo = l >> 4;     // k-octet selector
    const int tok0 = blockIdx.x * 128 + w * 16;
    const int kb   = blockIdx.y * KPER;

    const float* ax = x + (size_t)(tok0 + lr) * EMB + kb + lo * 8;

    // B staging: 24 gl_lds per 64-k chunk (192 rows x 128 B); wave w does
    // p=0..2 -> rows 24w+8p .. +7. Lane l -> row +(l>>3), shorts 8*(l&7).
    const unsigned short* gb[3];
#pragma unroll
    for (int p = 0; p < 3; ++p)
        gb[p] = Wp + (size_t)(24 * w + 8 * p + (l >> 3)) * EMB + kb + 8 * (l & 7);

    f32x4 accH[4], accL[4];
#pragma unroll
    for (int et = 0; et < 4; ++et) {
        accH[et] = (f32x4){0.f, 0.f, 0.f, 0.f};
        accL[et] = (f32x4){0.f, 0.f, 0.f, 0.f};
    }

    // prologue: stage chunk 0 -> buf 0; load A chunk 0 (4 float4: 2 halves)
#pragma unroll
    for (int p = 0; p < 3; ++p)
        gl_lds16(gb[p], &sB[0][24 * w + 8 * p][0]);
    float4 ac[2][2], an[2][2];
#pragma unroll
    for (int h = 0; h < 2; ++h) {
        ac[h][0] = *reinterpret_cast<const float4*>(ax + 32 * h);
        ac[h][1] = *reinterpret_cast<const float4*>(ax + 32 * h + 4);
    }

#pragma unroll 1
    for (int ks = 0; ks < NCH; ++ks) {
        const int buf = ks & 1;
        __syncthreads();   // drains own vmcnt: stage(ks) + A(ks) landed

        // issue next chunk's stage + A loads NOW (cover = this chunk's compute)
        if (ks + 1 < NCH) {
#pragma unroll
            for (int p = 0; p < 3; ++p)
                gl_lds16(gb[p] + (ks + 1) * BK, &sB[buf ^ 1][24 * w + 8 * p][0]);
        }
        const int nk = (ks + 1 < NCH ? ks + 1 : ks) * BK;   // clamped
#pragma unroll
        for (int h = 0; h < 2; ++h) {
            an[h][0] = *reinterpret_cast<const float4*>(ax + nk + 32 * h);
            an[h][1] = *reinterpret_cast<const float4*>(ax + nk + 32 * h + 4);
        }

        // compute the two 32-k halves of chunk ks
#pragma unroll
        for (int h = 0; h < 2; ++h) {
            short8 aH, aM, aL;
#pragma unroll
            for (int e = 0; e < 4; ++e) {
                unsigned short he, me, le;
                split3(reinterpret_cast<const float*>(&ac[h][0])[e], he, me, le);
                aH[e] = (short)he; aM[e] = (short)me; aL[e] = (short)le;
                split3(reinterpret_cast<const float*>(&ac[h][1])[e], he, me, le);
                aH[4 + e] = (short)he; aM[4 + e] = (short)me; aL[4 + e] = (short)le;
            }
#pragma unroll
            for (int et = 0; et < 4; ++et) {
                const unsigned short* bp = &sB[buf][et * 16 + lr][32 * h + lo * 8];
                const short8 bH = *reinterpret_cast<const short8*>(bp);
                const short8 bM = *reinterpret_cast<const short8*>(bp + 64 * BK);
                const short8 bL = *reinterpret_cast<const short8*>(bp + 128 * BK);
                accH[et] = __builtin_amdgcn_mfma_f32_16x16x32_bf16(aH, bH, accH[et], 0, 0, 0);
                accL[et] = __builtin_amdgcn_mfma_f32_16x16x32_bf16(aH, bM, accL[et], 0, 0, 0);
                accL[et] = __builtin_amdgcn_mfma_f32_16x16x32_bf16(aM, bH, accL[et], 0, 0, 0);
                accL[et] = __builtin_amdgcn_mfma_f32_16x16x32_bf16(aM, bM, accL[et], 0, 0, 0);
                accL[et] = __builtin_amdgcn_mfma_f32_16x16x32_bf16(aH, bL, accL[et], 0, 0, 0);
                accL[et] = __builtin_amdgcn_mfma_f32_16x16x32_bf16(aL, bH, accL[et], 0, 0, 0);
            }
        }
#pragma unroll
        for (int h = 0; h < 2; ++h) { ac[h][0] = an[h][0]; ac[h][1] = an[h][1]; }
    }

    // epilogue: per-wave transpose in LDS region aliased onto sB
    __syncthreads();   // all waves done reading sB before overwrite
    float* sled = reinterpret_cast<float*>(&sB[0][0][0]) + w * 1024; // 4 KB/wave
#pragma unroll
    for (int et = 0; et < 4; ++et)
#pragma unroll
        for (int j = 0; j < 4; ++j)
            sled[(et * 16 + lr) * 16 + lo * 4 + j] = accH[et][j] + accL[et][j];
    // own-wave read-after-write: compiler inserts lgkmcnt; no barrier needed
#pragma unroll
    for (int r = 0; r < 16; ++r) {
        const int e = 4 * r + lo;
        part[(size_t)(blockIdx.y * NEXP + e) * TOKENS + tok0 + lr]
            = sled[e * 16 + lr];
    }
}

// combine splits in fp64 + bias, top-2, softmax (R6-R9 proven).
template<int S>
__global__ __launch_bounds__(256) void reduce_topk(
    const float* __restrict__ part, const float* __restrict__ b,
    float* __restrict__ out)
{
    __shared__ double sv[64][4][2];
    __shared__ int    si[64][4][2];
    const int t    = threadIdx.x;
    const int p4   = t & 3;
    const int slot = t >> 2;
    const int tok  = blockIdx.x * 64 + slot;

    double v[16];
#pragma unroll
    for (int j = 0; j < 16; ++j) v[j] = 0.0;
    for (int s = 0; s < S; ++s)
#pragma unroll
        for (int j = 0; j < 16; ++j)
            v[j] += (double)part[(size_t)((s << 6) + (p4 << 4) + j) * TOKENS + tok];
#pragma unroll
    for (int j = 0; j < 16; ++j) v[j] += (double)b[(p4 << 4) + j];

    double v1 = -1e300, v2 = -1e300; int i1 = 0, i2 = 0;
#pragma unroll
    for (int j = 0; j < 16; ++j) {
        const int e = (p4 << 4) + j;
        if (v[j] > v1)      { v2 = v1; i2 = i1; v1 = v[j]; i1 = e; }
        else if (v[j] > v2) { v2 = v[j]; i2 = e; }
    }
    sv[slot][p4][0] = v1; sv[slot][p4][1] = v2;
    si[slot][p4][0] = i1; si[slot][p4][1] = i2;
    __syncthreads();

    if (p4 == 0) {
        double m1 = -1e300, m2 = -1e300; int j1 = 0, j2 = 0;
#pragma unroll
        for (int p = 0; p < 4; ++p)   // ascending parts: ties keep lowest idx
#pragma unroll
            for (int r = 0; r < 2; ++r) {
                const double vv = sv[slot][p][r]; const int ii = si[slot][p][r];
                if (vv > m1)      { m2 = m1; j2 = j1; m1 = vv; j1 = ii; }
                else if (vv > m2) { m2 = vv; j2 = ii; }
            }
        const float e2  = expf((float)(m2 - m1));   // <= 1
        const float inv = 1.0f / (1.0f + e2);
        out[2 * tok]     = (float)j1;
        out[2 * tok + 1] = (float)j2;
        out[2 * TOKENS + 2 * tok]     = inv;
        out[2 * TOKENS + 2 * tok + 1] = e2 * inv;
    }
}

extern "C" void kernel_launch(void* const* d_in, const int* in_sizes, int n_in,
                              void* d_out, int out_size, void* d_ws, size_t ws_size,
                              hipStream_t stream) {
    const float* x = (const float*)d_in[0];
    const float* W = (const float*)d_in[1];
    const float* b = (const float*)d_in[2];
    float* out = (float*)d_out;
    unsigned short* Wp = (unsigned short*)d_ws;
    float* part = (float*)d_ws + WP_FLOATS;

    split_w<<<dim3(NEXP * EMB / 1024), dim3(256), 0, stream>>>(W, Wp);

    const size_t base = (size_t)WP_FLOATS * 4;
    const size_t per  = (size_t)NEXP * TOKENS * 4;   // 4.19 MB / split
    if (ws_size >= base + 4 * per) {         // 18.3 MB (proven) -> 512 blocks
        router_mfma<4><<<dim3(TOKENS / 128, 4), dim3(512), 0, stream>>>(x, Wp, part);
        reduce_topk<4><<<dim3(TOKENS / 64), dim3(256), 0, stream>>>(part, b, out);
    } else if (ws_size >= base + 2 * per) {
        router_mfma<2><<<dim3(TOKENS / 128, 2), dim3(512), 0, stream>>>(x, Wp, part);
        reduce_topk<2><<<dim3(TOKENS / 64), dim3(256), 0, stream>>>(part, b, out);
    } else {
        router_mfma<1><<<dim3(TOKENS / 128, 1), dim3(512), 0, stream>>>(x, Wp, part);
        reduce_topk<1><<<dim3(TOKENS / 64), dim3(256), 0, stream>>>(part, b, out);
    }
}

// Round 11
// 80.999 us; speedup vs baseline: 2.0933x; 1.0255x over previous
//
#include <hip/hip_runtime.h>

#define TOKENS 16384
#define EMB 4096
#define NEXP 64
#define BK 64

typedef __attribute__((ext_vector_type(8))) short short8;
typedef __attribute__((ext_vector_type(4))) float f32x4;
typedef __attribute__((ext_vector_type(4))) unsigned short ush4;

#define WP_USHORTS (3 * NEXP * EMB)        // 1.5 MB bf16 W-planes (L2-resident)
#define WP_FLOATS  (WP_USHORTS / 2)

// async global->LDS, 16B/lane; dest = wave-uniform base + lane*16 (source per-lane)
__device__ __forceinline__ void gl_lds16(const void* g, void* lds) {
    __builtin_amdgcn_global_load_lds(
        (const __attribute__((address_space(1))) void*)g,
        (__attribute__((address_space(3))) void*)lds, 16, 0, 0);
}

// fp32 -> 3x bf16 (R7-R10 verified exact: absmax 0.0): hi RN, mid/lo trunc.
__device__ __forceinline__ void split3(float x, unsigned short& h,
                                       unsigned short& m, unsigned short& l) {
    unsigned u = __float_as_uint(x);
    unsigned r = u + 0x7FFFu + ((u >> 16) & 1u);
    float hF = __uint_as_float(r & 0xFFFF0000u);
    h = (unsigned short)(r >> 16);
    float r1 = x - hF;
    unsigned u1 = __float_as_uint(r1);
    float mF = __uint_as_float(u1 & 0xFFFF0000u);
    m = (unsigned short)(u1 >> 16);
    float r2 = r1 - mF;
    l = (unsigned short)(__float_as_uint(r2) >> 16);
}

// prep: split W into 3 bf16 planes Wp[plane][e][k] (flat row r = plane*64+e)
__global__ __launch_bounds__(256) void split_w(const float* __restrict__ W,
                                               unsigned short* __restrict__ Wp) {
    const int i = (blockIdx.x * 256 + threadIdx.x) * 4;
    const float4 v = *reinterpret_cast<const float4*>(W + i);
    ush4 h, m, l;
#pragma unroll
    for (int e = 0; e < 4; ++e) {
        unsigned short he, me, le;
        split3(reinterpret_cast<const float*>(&v)[e], he, me, le);
        h[e] = he; m[e] = me; l[e] = le;
    }
    *reinterpret_cast<ush4*>(Wp + i) = h;
    *reinterpret_cast<ush4*>(Wp + NEXP * EMB + i) = m;
    *reinterpret_cast<ush4*>(Wp + 2 * NEXP * EMB + i) = l;
}

// Main: MFMA split-3 bf16, counted-vmcnt 3-buffer pipeline (T4).
// Per iter ks: [s_waitcnt vmcnt(3); raw s_barrier; issue A(ks+1) (4 loads);
// issue stage(ks+2) (3 gl_lds); compute ks]. FIFO invariant: queue after
// the wait = [stage(ks+1)] (3 ops), so vmcnt(3) retires exactly stage(ks)
// and A(ks) each iter -> B-stage has >=1.5 iters of HBM cover and the
// barrier never drains the in-flight prefetch (R10's __syncthreads did).
// LDS: 3 x 24 KB buffers = 72 KB -> still 2 blocks/CU (staggered groups).
// Bank fix vs R10 (BK=64 collapsed reads to 4 quads, 16-way): XOR swizzle
// slot = kp ^ (row&7) realized by pre-swizzled gl_lds SOURCE (linear dest,
// same XOR on read) -> 8 addrs on each of 8 quads = b128 floor.
// Frag maps + precision identical to R7-R10 (absmax 0.0).
template<int S>
__global__ __launch_bounds__(512, 4) void router_mfma(
    const float* __restrict__ x, const unsigned short* __restrict__ Wp,
    float* __restrict__ part)
{
    constexpr int KPER = EMB / S;
    constexpr int NCH  = KPER / BK;

    __shared__ unsigned short sB[3][192][BK];   // 72 KB

    const int t  = threadIdx.x;
    const int w  = t >> 6;     // wave 0..7
    const int l  = t & 63;
    const int lr = l & 15;     // A token-row / B expert-col
    const int lo = l >> 4;     // k-octet selector
    const int tok0 = blockIdx.x * 128 + w * 16;
    const int kb   = blockIdx.y * KPER;

    const float* ax = x + (size_t)(tok0 + lr) * EMB + kb + lo * 8;

    // B staging: wave w, p=0..2 -> rows 24w+8p..+7; lane l -> row +(l>>3),
    // dest slot l&7; SOURCE k-piece = (l&7) ^ (row&7) = (l&7)^((l>>3)&7)
    const unsigned short* gb[3];
#pragma unroll
    for (int p = 0; p < 3; ++p)
        gb[p] = Wp + (size_t)(24 * w + 8 * p + (l >> 3)) * EMB + kb
              + 8 * ((l & 7) ^ ((l >> 3) & 7));

    f32x4 accH[4], accL[4];
#pragma unroll
    for (int et = 0; et < 4; ++et) {
        accH[et] = (f32x4){0.f, 0.f, 0.f, 0.f};
        accL[et] = (f32x4){0.f, 0.f, 0.f, 0.f};
    }

    // prologue: queue = [stage(0)(3), A(0)(4), stage(1)(3)]
    float4 ac[2][2], an[2][2];
#pragma unroll
    for (int p = 0; p < 3; ++p)
        gl_lds16(gb[p], &sB[0][24 * w + 8 * p][0]);
#pragma unroll
    for (int h = 0; h < 2; ++h) {
        ac[h][0] = *reinterpret_cast<const float4*>(ax + 32 * h);
        ac[h][1] = *reinterpret_cast<const float4*>(ax + 32 * h + 4);
    }
#pragma unroll
    for (int p = 0; p < 3; ++p)
        gl_lds16(gb[p] + BK, &sB[1][24 * w + 8 * p][0]);

    int buf = 0;                  // ks % 3
#pragma unroll 1
    for (int ks = 0; ks < NCH; ++ks) {
        // retire stage(ks)+A(ks); leave stage(ks+1) (3 ops) in flight
        asm volatile("s_waitcnt vmcnt(3)" ::: "memory");
        __builtin_amdgcn_s_barrier();   // raw: no vmcnt drain

        if (ks + 1 < NCH) {             // issue A(ks+1) first (stays oldest)
#pragma unroll
            for (int h = 0; h < 2; ++h) {
                an[h][0] = *reinterpret_cast<const float4*>(ax + (ks + 1) * BK + 32 * h);
                an[h][1] = *reinterpret_cast<const float4*>(ax + (ks + 1) * BK + 32 * h + 4);
            }
        }
        if (ks + 2 < NCH) {             // issue stage(ks+2) -> buf (ks+2)%3
            const int sb = (buf == 0) ? 2 : buf - 1;   // (ks+2)%3 == (ks-1)%3
#pragma unroll
            for (int p = 0; p < 3; ++p)
                gl_lds16(gb[p] + (ks + 2) * BK, &sB[sb][24 * w + 8 * p][0]);
        }
        __builtin_amdgcn_sched_barrier(0);   // pin issues before compute

        // compute chunk ks from sB[buf]
#pragma unroll
        for (int h = 0; h < 2; ++h) {
            short8 aH, aM, aL;
#pragma unroll
            for (int e = 0; e < 4; ++e) {
                unsigned short he, me, le;
                split3(reinterpret_cast<const float*>(&ac[h][0])[e], he, me, le);
                aH[e] = (short)he; aM[e] = (short)me; aL[e] = (short)le;
                split3(reinterpret_cast<const float*>(&ac[h][1])[e], he, me, le);
                aH[4 + e] = (short)he; aM[4 + e] = (short)me; aL[4 + e] = (short)le;
            }
#pragma unroll
            for (int et = 0; et < 4; ++et) {
                // read slot = kp ^ (row&7), kp = 4h+lo, row&7 = lr&7
                const int sw = (((4 * h + lo) ^ (lr & 7)) * 8);
                const unsigned short* bp = &sB[buf][et * 16 + lr][sw];
                const short8 bH = *reinterpret_cast<const short8*>(bp);
                const short8 bM = *reinterpret_cast<const short8*>(bp + 64 * BK);
                const short8 bL = *reinterpret_cast<const short8*>(bp + 128 * BK);
                accH[et] = __builtin_amdgcn_mfma_f32_16x16x32_bf16(aH, bH, accH[et], 0, 0, 0);
                accL[et] = __builtin_amdgcn_mfma_f32_16x16x32_bf16(aH, bM, accL[et], 0, 0, 0);
                accL[et] = __builtin_amdgcn_mfma_f32_16x16x32_bf16(aM, bH, accL[et], 0, 0, 0);
                accL[et] = __builtin_amdgcn_mfma_f32_16x16x32_bf16(aM, bM, accL[et], 0, 0, 0);
                accL[et] = __builtin_amdgcn_mfma_f32_16x16x32_bf16(aH, bL, accL[et], 0, 0, 0);
                accL[et] = __builtin_amdgcn_mfma_f32_16x16x32_bf16(aL, bH, accL[et], 0, 0, 0);
            }
        }
#pragma unroll
        for (int h = 0; h < 2; ++h) { ac[h][0] = an[h][0]; ac[h][1] = an[h][1]; }
        buf = (buf == 2) ? 0 : buf + 1;
    }

    // epilogue: full barrier (drains everything), per-wave transpose in LDS
    __syncthreads();
    float* sled = reinterpret_cast<float*>(&sB[0][0][0]) + w * 1024; // 4 KB/wave
#pragma unroll
    for (int et = 0; et < 4; ++et)
#pragma unroll
        for (int j = 0; j < 4; ++j)
            sled[(et * 16 + lr) * 16 + lo * 4 + j] = accH[et][j] + accL[et][j];
#pragma unroll
    for (int r = 0; r < 16; ++r) {
        const int e = 4 * r + lo;
        part[(size_t)(blockIdx.y * NEXP + e) * TOKENS + tok0 + lr]
            = sled[e * 16 + lr];
    }
}

// combine splits in fp64 + bias, top-2, softmax (R6-R10 proven).
template<int S>
__global__ __launch_bounds__(256) void reduce_topk(
    const float* __restrict__ part, const float* __restrict__ b,
    float* __restrict__ out)
{
    __shared__ double sv[64][4][2];
    __shared__ int    si[64][4][2];
    const int t    = threadIdx.x;
    const int p4   = t & 3;
    const int slot = t >> 2;
    const int tok  = blockIdx.x * 64 + slot;

    double v[16];
#pragma unroll
    for (int j = 0; j < 16; ++j) v[j] = 0.0;
    for (int s = 0; s < S; ++s)
#pragma unroll
        for (int j = 0; j < 16; ++j)
            v[j] += (double)part[(size_t)((s << 6) + (p4 << 4) + j) * TOKENS + tok];
#pragma unroll
    for (int j = 0; j < 16; ++j) v[j] += (double)b[(p4 << 4) + j];

    double v1 = -1e300, v2 = -1e300; int i1 = 0, i2 = 0;
#pragma unroll
    for (int j = 0; j < 16; ++j) {
        const int e = (p4 << 4) + j;
        if (v[j] > v1)      { v2 = v1; i2 = i1; v1 = v[j]; i1 = e; }
        else if (v[j] > v2) { v2 = v[j]; i2 = e; }
    }
    sv[slot][p4][0] = v1; sv[slot][p4][1] = v2;
    si[slot][p4][0] = i1; si[slot][p4][1] = i2;
    __syncthreads();

    if (p4 == 0) {
        double m1 = -1e300, m2 = -1e300; int j1 = 0, j2 = 0;
#pragma unroll
        for (int p = 0; p < 4; ++p)   // ascending parts: ties keep lowest idx
#pragma unroll
            for (int r = 0; r < 2; ++r) {
                const double vv = sv[slot][p][r]; const int ii = si[slot][p][r];
                if (vv > m1)      { m2 = m1; j2 = j1; m1 = vv; j1 = ii; }
                else if (vv > m2) { m2 = vv; j2 = ii; }
            }
        const float e2  = expf((float)(m2 - m1));   // <= 1
        const float inv = 1.0f / (1.0f + e2);
        out[2 * tok]     = (float)j1;
        out[2 * tok + 1] = (float)j2;
        out[2 * TOKENS + 2 * tok]     = inv;
        out[2 * TOKENS + 2 * tok + 1] = e2 * inv;
    }
}

extern "C" void kernel_launch(void* const* d_in, const int* in_sizes, int n_in,
                              void* d_out, int out_size, void* d_ws, size_t ws_size,
                              hipStream_t stream) {
    const float* x = (const float*)d_in[0];
    const float* W = (const float*)d_in[1];
    const float* b = (const float*)d_in[2];
    float* out = (float*)d_out;
    unsigned short* Wp = (unsigned short*)d_ws;
    float* part = (float*)d_ws + WP_FLOATS;

    split_w<<<dim3(NEXP * EMB / 1024), dim3(256), 0, stream>>>(W, Wp);

    const size_t base = (size_t)WP_FLOATS * 4;
    const size_t per  = (size_t)NEXP * TOKENS * 4;   // 4.19 MB / split
    if (ws_size >= base + 4 * per) {         // 18.3 MB (proven) -> 512 blocks
        router_mfma<4><<<dim3(TOKENS / 128, 4), dim3(512), 0, stream>>>(x, Wp, part);
        reduce_topk<4><<<dim3(TOKENS / 64), dim3(256), 0, stream>>>(part, b, out);
    } else if (ws_size >= base + 2 * per) {
        router_mfma<2><<<dim3(TOKENS / 128, 2), dim3(512), 0, stream>>>(x, Wp, part);
        reduce_topk<2><<<dim3(TOKENS / 64), dim3(256), 0, stream>>>(part, b, out);
    } else {
        router_mfma<1><<<dim3(TOKENS / 128, 1), dim3(512), 0, stream>>>(x, Wp, part);
        reduce_topk<1><<<dim3(TOKENS / 64), dim3(256), 0, stream>>>(part, b, out);
    }
}